// Round 18
// baseline (394.034 us; speedup 1.0000x reference)
//
#include <hip/hip_runtime.h>
#include <hip/hip_cooperative_groups.h>

namespace cg = cooperative_groups;

constexpr int N_NODES = 50000;
constexpr int N_EDGES = 800000;
constexpr float BN_EPS = 1e-5f;
constexpr int BNA_BLOCKS = 256;
constexpr int EBLK = 256;            // edge blocks for radix pass 1
constexpr int EPB = N_EDGES / EBLK;  // 3125 (exact)
constexpr int NBUCK = (N_NODES + 255) / 256;  // 196 row-buckets

typedef __attribute__((ext_vector_type(8))) short short8;
typedef __attribute__((ext_vector_type(4))) float f32x4;
typedef __attribute__((ext_vector_type(2))) float f32x2;

__device__ __forceinline__ float bf2f(ushort u) {
  union { uint i; float f; } v;
  v.i = ((uint)u) << 16;
  return v.f;
}
__device__ __forceinline__ ushort f2bf(float f) {
  union { float f; uint i; } v;
  v.f = f;
  uint r = v.i + 0x7fff + ((v.i >> 16) & 1);  // RNE
  return (ushort)(r >> 16);
}
__device__ __forceinline__ uchar f2fp8(float v) {
  int r = __builtin_amdgcn_cvt_pk_fp8_f32(v, 0.f, 0, false);
  return (uchar)(r & 0xff);
}
__device__ __forceinline__ void dec4(uint w, float* o) {
  f32x2 lo = __builtin_amdgcn_cvt_pk_f32_fp8(w, false);
  f32x2 hi = __builtin_amdgcn_cvt_pk_f32_fp8(w, true);
  o[0] = lo.x;
  o[1] = lo.y;
  o[2] = hi.x;
  o[3] = hi.y;
}

// ============ cooperative front-end: CSR build (radix sort by row) + W transposes =====
// 256 blocks x 256 threads. Phases:
//  1. per-edge-block histogram of row>>8  (+ W0/W1/W2 -> bf16 transposed, interleaved)
//  2. per-bucket prefix over blocks (block b = bucket b)
//  3. global bucket prefix (block 0)
//  4. scatter edges into buckets, packed (row&255)<<16 | col
//  5. in-bucket sort by row&255 -> col_sorted, row_start, dis
__global__ __launch_bounds__(256) void k_front(const int* __restrict__ erow,
                                               const int* __restrict__ ecol,
                                               const float* __restrict__ W0,
                                               const float* __restrict__ W1,
                                               const float* __restrict__ W2,
                                               ushort* __restrict__ Wt0,
                                               ushort* __restrict__ Wt1,
                                               ushort* __restrict__ Wt2,
                                               int* __restrict__ bh, int* __restrict__ bhoff,
                                               int* __restrict__ btot,
                                               int* __restrict__ bucketStart,
                                               int* __restrict__ ebuf,
                                               int* __restrict__ col_sorted,
                                               int* __restrict__ row_start,
                                               float* __restrict__ dis) {
  cg::grid_group grid = cg::this_grid();
  __shared__ int sm[1024];
  const int b = blockIdx.x, t = threadIdx.x;

  // ---- phase 1: histogram + wt ----
  {
    int* h = sm;
    h[t] = 0;
    __syncthreads();
    int base = b * EPB;
    for (int i = t; i < EPB; i += 256) atomicAdd(&h[erow[base + i] >> 8], 1);
    // interleave W transposes (independent)
    for (int idx = b * 256 + t; idx < 163840; idx += 65536) {
      if (idx < 65536) {
        Wt0[idx] = f2bf(W0[(idx & 255) * 256 + (idx >> 8)]);
      } else if (idx < 131072) {
        int l = idx - 65536;
        Wt1[l] = f2bf(W1[(l & 255) * 256 + (l >> 8)]);
      } else {
        int l = idx - 131072;
        Wt2[l] = f2bf(W2[(l & 255) * 128 + (l >> 8)]);
      }
    }
    __syncthreads();
    bh[b * 256 + t] = h[t];
  }
  grid.sync();

  // ---- phase 2: per-bucket prefix over blocks (block b = bucket b) ----
  {
    int* s = sm;
    int v = bh[t * 256 + b];
    s[t] = v;
    __syncthreads();
    for (int off = 1; off < 256; off <<= 1) {
      int x = (t >= off) ? s[t - off] : 0;
      __syncthreads();
      s[t] += x;
      __syncthreads();
    }
    bhoff[t * 256 + b] = s[t] - v;
    if (t == 255) btot[b] = s[255];
  }
  grid.sync();

  // ---- phase 3: global bucket prefix (block 0) ----
  if (b == 0) {
    int* s = sm;
    int v = btot[t];
    s[t] = v;
    __syncthreads();
    for (int off = 1; off < 256; off <<= 1) {
      int x = (t >= off) ? s[t - off] : 0;
      __syncthreads();
      s[t] += x;
      __syncthreads();
    }
    bucketStart[t] = s[t] - v;
    if (t == 0) row_start[N_NODES] = N_EDGES;
  }
  grid.sync();

  // ---- phase 4: scatter into buckets ----
  {
    int* fl = sm;
    fl[t] = 0;
    __syncthreads();
    int base = b * EPB;
    for (int i = t; i < EPB; i += 256) {
      int r = erow[base + i], c = ecol[base + i];
      int bin = r >> 8;
      int rk = atomicAdd(&fl[bin], 1);
      ebuf[bucketStart[bin] + bhoff[b * 256 + bin] + rk] = ((r & 255) << 16) | c;
    }
  }
  grid.sync();

  // ---- phase 5: in-bucket sort (blocks 0..NBUCK-1) ----
  if (b < NBUCK) {
    int* h = sm;
    int* pex = sm + 256;
    int* fl = sm + 512;
    int* sc = sm + 768;
    int base = bucketStart[b], n = btot[b];
    h[t] = 0;
    fl[t] = 0;
    __syncthreads();
    for (int i = t; i < n; i += 256) atomicAdd(&h[ebuf[base + i] >> 16], 1);
    __syncthreads();
    int v = h[t];
    sc[t] = v;
    __syncthreads();
    for (int off = 1; off < 256; off <<= 1) {
      int x = (t >= off) ? sc[t - off] : 0;
      __syncthreads();
      sc[t] += x;
      __syncthreads();
    }
    pex[t] = sc[t] - v;
    int row = b * 256 + t;
    if (row < N_NODES) {
      row_start[row] = base + pex[t];
      dis[row] = rsqrtf((float)(v + 1));
    }
    __syncthreads();
    for (int i = t; i < n; i += 256) {
      int e = ebuf[base + i];
      int rl = e >> 16;
      int rk = atomicAdd(&fl[rl], 1);
      col_sorted[base + pex[rl] + rk] = e & 0xFFFF;
    }
  }
}

// ---------------- bf16 MFMA GEMM, BK=64: hs = cvt( f(A) @ W * d_isqrt ) ----------------
template <int D, bool APPLY_BN, bool OUT_FP8>
__global__ __launch_bounds__(128 * (D / 64)) void k_gemm_bf16(const void* __restrict__ Av,
                                                              const ushort* __restrict__ Wt,
                                                              const float* __restrict__ ss,
                                                              const float* __restrict__ dis,
                                                              void* __restrict__ hsv) {
  constexpr int THREADS = 128 * (D / 64);  // 512 (D=256) / 256 (D=128)
  constexpr int BM = 128, BK = 64, K = 256;
  constexpr int WC = D / 64;
  constexpr int LDP = BK + 8;  // 72 bf16 (144B) stride
  __shared__ ushort As[BM * LDP];
  __shared__ ushort Bs[D * LDP];
  const int tid = threadIdx.x;
  const int lane = tid & 63;
  const int wid = tid >> 6;
  const int wr = wid / WC, wc = wid % WC;
  const int rb = blockIdx.x * BM;

  f32x4 acc[4][4];
#pragma unroll
  for (int m = 0; m < 4; ++m)
#pragma unroll
    for (int n = 0; n < 4; ++n) acc[m][n] = (f32x4)(0.f);

  for (int kt = 0; kt < K; kt += BK) {
#pragma unroll
    for (int it = 0; it < 1024 / THREADS; ++it) {
      int idx = tid + it * THREADS;
      int row = idx >> 3, kq = idx & 7;
      int gr = rb + row;
      if (gr >= N_NODES) gr = N_NODES - 1;
      float e[8];
      if constexpr (APPLY_BN) {
        const ushort* A = (const ushort*)Av;
        short8 v = *reinterpret_cast<const short8*>(&A[(size_t)gr * K + kt + kq * 8]);
#pragma unroll
        for (int q = 0; q < 8; ++q) {
          int k = kt + kq * 8 + q;
          e[q] = fmaxf(bf2f((ushort)v[q]) * ss[k] + ss[256 + k], 0.f);
        }
      } else {
        const float* A = (const float*)Av;
        const float4* src = reinterpret_cast<const float4*>(&A[(size_t)gr * K + kt + kq * 8]);
        float4 v0 = src[0], v1 = src[1];
        e[0] = v0.x; e[1] = v0.y; e[2] = v0.z; e[3] = v0.w;
        e[4] = v1.x; e[5] = v1.y; e[6] = v1.z; e[7] = v1.w;
      }
      short8 pk;
#pragma unroll
      for (int q = 0; q < 8; ++q) pk[q] = (short)f2bf(e[q]);
      *reinterpret_cast<short8*>(&As[row * LDP + kq * 8]) = pk;
    }
#pragma unroll
    for (int it = 0; it < D * 8 / THREADS; ++it) {
      int idx = tid + it * THREADS;
      int n = idx >> 3, kq = idx & 7;
      short8 v = *reinterpret_cast<const short8*>(&Wt[(size_t)n * K + kt + kq * 8]);
      *reinterpret_cast<short8*>(&Bs[n * LDP + kq * 8]) = v;
    }
    __syncthreads();

    const int rl = lane & 15;
#pragma unroll
    for (int ks = 0; ks < 2; ++ks) {
      const int kb = ks * 32 + (lane >> 4) * 8;
      short8 af[4], bfr[4];
#pragma unroll
      for (int f = 0; f < 4; ++f) {
        af[f] = *reinterpret_cast<short8*>(&As[(wr * 64 + f * 16 + rl) * LDP + kb]);
        bfr[f] = *reinterpret_cast<short8*>(&Bs[(wc * 64 + f * 16 + rl) * LDP + kb]);
      }
#pragma unroll
      for (int m = 0; m < 4; ++m)
#pragma unroll
        for (int n = 0; n < 4; ++n)
          acc[m][n] = __builtin_amdgcn_mfma_f32_16x16x32_bf16(af[m], bfr[n], acc[m][n], 0, 0, 0);
    }
    __syncthreads();
  }

  const int cl = lane & 15;
  const int rq = lane >> 4;
#pragma unroll
  for (int m = 0; m < 4; ++m) {
    int rbase = rb + wr * 64 + m * 16 + rq * 4;
#pragma unroll
    for (int j = 0; j < 4; ++j) {
      int row = rbase + j;
      if (row >= N_NODES) continue;
      float di = dis[row];
#pragma unroll
      for (int n = 0; n < 4; ++n) {
        int col = wc * 64 + n * 16 + cl;
        if constexpr (OUT_FP8) {
          ((uchar*)hsv)[(size_t)row * D + col] = f2fp8(acc[m][n][j] * di);
        } else {
          ((ushort*)hsv)[(size_t)row * D + col] = f2bf(acc[m][n][j] * di);
        }
      }
    }
  }
}

// ---------------- fp8 aggregation: pre = bf16(dis*(self+sum_nbr)+b) ----------------
__global__ __launch_bounds__(256) void k_agg_fp8(const uchar* __restrict__ hs8,
                                                 const int* __restrict__ cs,
                                                 const int* __restrict__ rs,
                                                 const float* __restrict__ dis,
                                                 const float* __restrict__ bias,
                                                 ushort* __restrict__ pre) {
  int gw = (blockIdx.x * 256 + threadIdx.x) >> 6;
  if (gw >= N_NODES) return;
  const int lane = threadIdx.x & 63;
  const int quad = lane >> 4;
  const int c16 = lane & 15;
  const size_t coff = (size_t)c16 * 16;

  float a[16];
  {
    uint4 sv = *reinterpret_cast<const uint4*>(&hs8[(size_t)gw * 256 + coff]);
    float tmp[16];
    dec4(sv.x, tmp);
    dec4(sv.y, tmp + 4);
    dec4(sv.z, tmp + 8);
    dec4(sv.w, tmp + 12);
#pragma unroll
    for (int q = 0; q < 16; ++q) a[q] = quad ? 0.f : tmp[q];
  }

  int s = rs[gw], e = rs[gw + 1];
  for (int base = s; base < e; base += 64) {
    int nav = min(64, e - base);
    int idx = (base + lane < e) ? cs[base + lane] : 0;
    int j = 0;
    for (; j + 16 <= nav; j += 16) {  // 16 edges: 4 loads in flight
      uint4 v[4];
#pragma unroll
      for (int u = 0; u < 4; ++u) {
        int c = __shfl(idx, j + 4 * u + quad);
        v[u] = *reinterpret_cast<const uint4*>(&hs8[(size_t)((uint)c) * 256 + coff]);
      }
#pragma unroll
      for (int u = 0; u < 4; ++u) {
        float tmp[16];
        dec4(v[u].x, tmp);
        dec4(v[u].y, tmp + 4);
        dec4(v[u].z, tmp + 8);
        dec4(v[u].w, tmp + 12);
#pragma unroll
        for (int q = 0; q < 16; ++q) a[q] += tmp[q];
      }
    }
    for (; j < nav; j += 4) {  // tail: weight-folded quad-load
      int je = j + quad;
      int c = __shfl(idx, je & 63);
      float w = (je < nav) ? 1.f : 0.f;
      uint4 v = *reinterpret_cast<const uint4*>(&hs8[(size_t)((uint)c) * 256 + coff]);
      float tmp[16];
      dec4(v.x, tmp);
      dec4(v.y, tmp + 4);
      dec4(v.z, tmp + 8);
      dec4(v.w, tmp + 12);
#pragma unroll
      for (int q = 0; q < 16; ++q) a[q] = fmaf(w, tmp[q], a[q]);
    }
  }
#pragma unroll
  for (int q = 0; q < 16; ++q) {
    a[q] += __shfl_xor(a[q], 16);
    a[q] += __shfl_xor(a[q], 32);
  }

  if (quad == 0) {
    float di = dis[gw];
    float bb[16];
#pragma unroll
    for (int p = 0; p < 4; ++p) {
      float4 b = *reinterpret_cast<const float4*>(&bias[coff + p * 4]);
      bb[p * 4] = b.x;
      bb[p * 4 + 1] = b.y;
      bb[p * 4 + 2] = b.z;
      bb[p * 4 + 3] = b.w;
    }
    short8 o0, o1;
#pragma unroll
    for (int q = 0; q < 8; ++q) {
      o0[q] = (short)f2bf(a[q] * di + bb[q]);
      o1[q] = (short)f2bf(a[8 + q] * di + bb[8 + q]);
    }
    *reinterpret_cast<short8*>(&pre[(size_t)gw * 256 + coff]) = o0;
    *reinterpret_cast<short8*>(&pre[(size_t)gw * 256 + coff + 8]) = o1;
  }
}

// layer-3 agg + log_softmax: D=128 bf16 row = 256B = 16 lanes x short8; 4 edges/instr.
__global__ __launch_bounds__(256) void k_agg_lsm_bf16(const ushort* __restrict__ hs,
                                                      const int* __restrict__ cs,
                                                      const int* __restrict__ rs,
                                                      const float* __restrict__ dis,
                                                      const float* __restrict__ bias,
                                                      float* __restrict__ out) {
  int gw = (blockIdx.x * 256 + threadIdx.x) >> 6;
  if (gw >= N_NODES) return;
  const int lane = threadIdx.x & 63;
  const int quad = lane >> 4;
  const int c8 = lane & 15;
  const size_t coff = (size_t)c8 * 8;

  float a[8];
  short8 sv = *reinterpret_cast<const short8*>(&hs[(size_t)gw * 128 + coff]);
#pragma unroll
  for (int q = 0; q < 8; ++q) a[q] = quad ? 0.f : bf2f((ushort)sv[q]);

  int s = rs[gw], e = rs[gw + 1];
  for (int base = s; base < e; base += 64) {
    int nav = min(64, e - base);
    int idx = (base + lane < e) ? cs[base + lane] : 0;
    int j = 0;
    for (; j + 16 <= nav; j += 16) {
      short8 v[4];
#pragma unroll
      for (int u = 0; u < 4; ++u) {
        int c = __shfl(idx, j + 4 * u + quad);
        v[u] = *reinterpret_cast<const short8*>(&hs[(size_t)((uint)c) * 128 + coff]);
      }
#pragma unroll
      for (int u = 0; u < 4; ++u)
#pragma unroll
        for (int q = 0; q < 8; ++q) a[q] += bf2f((ushort)v[u][q]);
    }
    for (; j < nav; j += 4) {
      int je = j + quad;
      int c = __shfl(idx, je & 63);
      float w = (je < nav) ? 1.f : 0.f;
      short8 v = *reinterpret_cast<const short8*>(&hs[(size_t)((uint)c) * 128 + coff]);
#pragma unroll
      for (int q = 0; q < 8; ++q) a[q] = fmaf(w, bf2f((ushort)v[q]), a[q]);
    }
  }
#pragma unroll
  for (int q = 0; q < 8; ++q) {
    a[q] += __shfl_xor(a[q], 16);
    a[q] += __shfl_xor(a[q], 32);
  }

  float di = dis[gw];
  float4 b0 = *reinterpret_cast<const float4*>(&bias[c8 * 8]);
  float4 b1 = *reinterpret_cast<const float4*>(&bias[c8 * 8 + 4]);
  float bb[8] = {b0.x, b0.y, b0.z, b0.w, b1.x, b1.y, b1.z, b1.w};
  float vv[8];
  float m = -1e30f;
#pragma unroll
  for (int q = 0; q < 8; ++q) {
    vv[q] = a[q] * di + bb[q];
    m = fmaxf(m, vv[q]);
  }
#pragma unroll
  for (int o = 1; o < 16; o <<= 1) m = fmaxf(m, __shfl_xor(m, o));
  float sum = 0.f;
#pragma unroll
  for (int q = 0; q < 8; ++q) sum += __expf(vv[q] - m);
#pragma unroll
  for (int o = 1; o < 16; o <<= 1) sum += __shfl_xor(sum, o);
  float ls = m + logf(sum);
  if (quad == 0) {
    float4 o0 = {vv[0] - ls, vv[1] - ls, vv[2] - ls, vv[3] - ls};
    float4 o1 = {vv[4] - ls, vv[5] - ls, vv[6] - ls, vv[7] - ls};
    *reinterpret_cast<float4*>(&out[(size_t)gw * 128 + coff]) = o0;
    *reinterpret_cast<float4*>(&out[(size_t)gw * 128 + coff + 4]) = o1;
  }
}

// ---------------- batchnorm stats: three-phase, atomic-free ----------------
__global__ __launch_bounds__(256) void k_bnstatsA(const ushort* __restrict__ pre,
                                                  float* __restrict__ partial) {
  int t = threadIdx.x;
  int rsub = t >> 7;
  int cp = (t & 127) * 2;
  float s0 = 0.f, s1 = 0.f, q0 = 0.f, q1 = 0.f;
  for (int r = blockIdx.x * 2 + rsub; r < N_NODES; r += BNA_BLOCKS * 2) {
    ushort2 v = *reinterpret_cast<const ushort2*>(&pre[(size_t)r * 256 + cp]);
    float f0 = bf2f(v.x), f1 = bf2f(v.y);
    s0 += f0;
    q0 += f0 * f0;
    s1 += f1;
    q1 += f1 * f1;
  }
  __shared__ float lsum[256], lsq[256];
  if (rsub) {
    lsum[cp] = s0;
    lsum[cp + 1] = s1;
    lsq[cp] = q0;
    lsq[cp + 1] = q1;
  }
  __syncthreads();
  if (!rsub) {
    float* p = &partial[(size_t)blockIdx.x * 512];
    p[cp] = s0 + lsum[cp];
    p[cp + 1] = s1 + lsum[cp + 1];
    p[256 + cp] = q0 + lsq[cp];
    p[256 + cp + 1] = q1 + lsq[cp + 1];
  }
}

__global__ __launch_bounds__(512) void k_bnstatsB(const float* __restrict__ partial,
                                                  float* __restrict__ p2) {
  int t = threadIdx.x, b = blockIdx.x;
  float a = 0.f;
#pragma unroll 8
  for (int r = 0; r < BNA_BLOCKS / 8; ++r)
    a += partial[(size_t)(b * (BNA_BLOCKS / 8) + r) * 512 + t];
  p2[(size_t)b * 512 + t] = a;
}

__global__ void k_bnfinal(const float* __restrict__ p2, const float* __restrict__ gamma,
                          const float* __restrict__ beta, float* __restrict__ ss) {
  int t = threadIdx.x;
  float sum = 0.f, sq = 0.f;
#pragma unroll
  for (int b = 0; b < 8; ++b) {
    sum += p2[(size_t)b * 512 + t];
    sq += p2[(size_t)b * 512 + 256 + t];
  }
  float mu = sum * (1.f / N_NODES);
  float var = sq * (1.f / N_NODES) - mu * mu;
  float sc = gamma[t] * rsqrtf(var + BN_EPS);
  ss[t] = sc;
  ss[256 + t] = beta[t] - mu * sc;
}

// ---------------- launcher ----------------
extern "C" void kernel_launch(void* const* d_in, const int* in_sizes, int n_in,
                              void* d_out, int out_size, void* d_ws, size_t ws_size,
                              hipStream_t stream) {
  const float* x = (const float*)d_in[0];
  const int* erow = (const int*)d_in[1];
  const int* ecol = erow + N_EDGES;
  const float* W0 = (const float*)d_in[2];
  const float* b0 = (const float*)d_in[3];
  const float* W1 = (const float*)d_in[4];
  const float* b1 = (const float*)d_in[5];
  const float* W2 = (const float*)d_in[6];
  const float* b2 = (const float*)d_in[7];
  const float* g0 = (const float*)d_in[8];
  const float* be0 = (const float*)d_in[9];
  const float* g1 = (const float*)d_in[10];
  const float* be1 = (const float*)d_in[11];
  float* out = (float*)d_out;

  char* ws = (char*)d_ws;
  size_t off = 0;
  auto take = [&](size_t bytes) {
    char* p = ws + off;
    off = (off + bytes + 255) & ~(size_t)255;
    return p;
  };
  int* bh = (int*)take(256 * 256 * 4);
  int* bhoff = (int*)take(256 * 256 * 4);
  int* btot = (int*)take(256 * 4);
  int* bucketStart = (int*)take(256 * 4);
  int* ebuf = (int*)take((size_t)N_EDGES * 4);
  int* row_start = (int*)take((N_NODES + 1) * 4);
  float* bnpart = (float*)take((size_t)BNA_BLOCKS * 512 * 4);
  float* bnpart2 = (float*)take(8 * 512 * 4);
  float* dis = (float*)take(N_NODES * 4);
  float* ss0 = (float*)take(512 * 4);
  float* ss1 = (float*)take(512 * 4);
  ushort* Wt0 = (ushort*)take(256 * 256 * 2);
  ushort* Wt1 = (ushort*)take(256 * 256 * 2);
  ushort* Wt2 = (ushort*)take(256 * 128 * 2);
  int* col_sorted = (int*)take((size_t)N_EDGES * 4);
  uchar* hs8 = (uchar*)take((size_t)N_NODES * 256);        // fp8 gather operand (L0/L1)
  ushort* hs = (ushort*)take((size_t)N_NODES * 128 * 2);   // bf16 (L2)
  ushort* pre = (ushort*)take((size_t)N_NODES * 256 * 2);  // bf16
  if (off > ws_size) return;

  // cooperative front-end: CSR build + W transposes in ONE launch
  {
    void* args[] = {(void*)&erow, (void*)&ecol, (void*)&W0,  (void*)&W1,
                    (void*)&W2,   (void*)&Wt0,  (void*)&Wt1, (void*)&Wt2,
                    (void*)&bh,   (void*)&bhoff, (void*)&btot, (void*)&bucketStart,
                    (void*)&ebuf, (void*)&col_sorted, (void*)&row_start, (void*)&dis};
    hipLaunchCooperativeKernel((void*)k_front, dim3(256), dim3(256), args, 0, stream);
  }

  int mblocks = (N_NODES + 127) / 128;        // 391
  int agg_grid = (N_NODES * 64 + 255) / 256;  // 12500
  // layer 0 (hs fp8)
  k_gemm_bf16<256, false, true><<<mblocks, 512, 0, stream>>>(x, Wt0, nullptr, dis, hs8);
  k_agg_fp8<<<agg_grid, 256, 0, stream>>>(hs8, col_sorted, row_start, dis, b0, pre);
  k_bnstatsA<<<BNA_BLOCKS, 256, 0, stream>>>(pre, bnpart);
  k_bnstatsB<<<8, 512, 0, stream>>>(bnpart, bnpart2);
  k_bnfinal<<<1, 256, 0, stream>>>(bnpart2, g0, be0, ss0);
  // layer 1 (hs fp8)
  k_gemm_bf16<256, true, true><<<mblocks, 512, 0, stream>>>(pre, Wt1, ss0, dis, hs8);
  k_agg_fp8<<<agg_grid, 256, 0, stream>>>(hs8, col_sorted, row_start, dis, b1, pre);
  k_bnstatsA<<<BNA_BLOCKS, 256, 0, stream>>>(pre, bnpart);
  k_bnstatsB<<<8, 512, 0, stream>>>(bnpart, bnpart2);
  k_bnfinal<<<1, 256, 0, stream>>>(bnpart2, g1, be1, ss1);
  // layer 2 (bf16) + fused log_softmax
  k_gemm_bf16<128, true, false><<<mblocks, 256, 0, stream>>>(pre, Wt2, ss1, dis, hs);
  k_agg_lsm_bf16<<<agg_grid, 256, 0, stream>>>(hs, col_sorted, row_start, dis, b2, out);
}

// Round 19
// 260.163 us; speedup vs baseline: 1.5146x; 1.5146x over previous
//
#include <hip/hip_runtime.h>

constexpr int N_NODES = 50000;
constexpr int N_EDGES = 800000;
constexpr float BN_EPS = 1e-5f;
constexpr int BNA_BLOCKS = 256;
constexpr int EBLK = 256;            // edge blocks for radix pass 1
constexpr int EPB = N_EDGES / EBLK;  // 3125 (exact)
constexpr int NBUCK = (N_NODES + 255) / 256;  // 196 row-buckets

typedef __attribute__((ext_vector_type(8))) short short8;
typedef __attribute__((ext_vector_type(4))) float f32x4;
typedef __attribute__((ext_vector_type(2))) float f32x2;

__device__ __forceinline__ float bf2f(ushort u) {
  union { uint i; float f; } v;
  v.i = ((uint)u) << 16;
  return v.f;
}
__device__ __forceinline__ ushort f2bf(float f) {
  union { float f; uint i; } v;
  v.f = f;
  uint r = v.i + 0x7fff + ((v.i >> 16) & 1);  // RNE
  return (ushort)(r >> 16);
}
__device__ __forceinline__ uchar f2fp8(float v) {
  int r = __builtin_amdgcn_cvt_pk_fp8_f32(v, 0.f, 0, false);
  return (uchar)(r & 0xff);
}
__device__ __forceinline__ void dec4(uint w, float* o) {
  f32x2 lo = __builtin_amdgcn_cvt_pk_f32_fp8(w, false);
  f32x2 hi = __builtin_amdgcn_cvt_pk_f32_fp8(w, true);
  o[0] = lo.x;
  o[1] = lo.y;
  o[2] = hi.x;
  o[3] = hi.y;
}

// ================= CSR build: atomic-free 2-pass radix sort by row =================
__global__ __launch_bounds__(256) void k_ehist(const int* __restrict__ erow,
                                               int* __restrict__ bh) {
  __shared__ int h[256];
  int t = threadIdx.x;
  h[t] = 0;
  __syncthreads();
  int base = blockIdx.x * EPB;
  for (int i = t; i < EPB; i += 256) atomicAdd(&h[erow[base + i] >> 8], 1);
  __syncthreads();
  bh[blockIdx.x * 256 + t] = h[t];
}

__global__ void k_binscanA(const int* __restrict__ bh, int* __restrict__ bhoff,
                           int* __restrict__ btot, int nb) {
  __shared__ int s[256];
  int b = blockIdx.x;   // bucket
  int t = threadIdx.x;  // edge-block index
  int v = (t < nb) ? bh[t * 256 + b] : 0;
  s[t] = v;
  __syncthreads();
  for (int off = 1; off < 256; off <<= 1) {
    int x = (t >= off) ? s[t - off] : 0;
    __syncthreads();
    s[t] += x;
    __syncthreads();
  }
  if (t < nb) bhoff[t * 256 + b] = s[t] - v;
  if (t == 255) btot[b] = s[255];
}

__global__ void k_binscanB(const int* __restrict__ btot, int* __restrict__ bucketStart,
                           int* __restrict__ row_start) {
  __shared__ int s[256];
  int t = threadIdx.x;
  int v = btot[t];
  s[t] = v;
  __syncthreads();
  for (int off = 1; off < 256; off <<= 1) {
    int x = (t >= off) ? s[t - off] : 0;
    __syncthreads();
    s[t] += x;
    __syncthreads();
  }
  bucketStart[t] = s[t] - v;  // exclusive
  if (t == 0) row_start[N_NODES] = N_EDGES;
}

__global__ __launch_bounds__(256) void k_escatter(const int* __restrict__ erow,
                                                  const int* __restrict__ ecol,
                                                  const int* __restrict__ bucketStart,
                                                  const int* __restrict__ bhoff,
                                                  int* __restrict__ ebuf) {
  __shared__ int fl[256];
  int t = threadIdx.x;
  fl[t] = 0;
  __syncthreads();
  int b = blockIdx.x, base = b * EPB;
  for (int i = t; i < EPB; i += 256) {
    int r = erow[base + i], c = ecol[base + i];
    int bin = r >> 8;
    int rk = atomicAdd(&fl[bin], 1);
    int pos = bucketStart[bin] + bhoff[b * 256 + bin] + rk;
    ebuf[pos] = ((r & 255) << 16) | c;
  }
}

// pass 3: sort within bucket, emit row_start/dis/col_sorted
__global__ __launch_bounds__(256) void k_esort(const int* __restrict__ ebuf,
                                               const int* __restrict__ bucketStart,
                                               const int* __restrict__ btot,
                                               int* __restrict__ col_sorted,
                                               int* __restrict__ row_start,
                                               float* __restrict__ dis) {
  __shared__ int h[256], pex[256], fl[256], sc[256];
  int bin = blockIdx.x, t = threadIdx.x;
  int base = bucketStart[bin], n = btot[bin];
  h[t] = 0;
  fl[t] = 0;
  __syncthreads();
  for (int i = t; i < n; i += 256) atomicAdd(&h[ebuf[base + i] >> 16], 1);
  __syncthreads();
  int v = h[t];
  sc[t] = v;
  __syncthreads();
  for (int off = 1; off < 256; off <<= 1) {
    int x = (t >= off) ? sc[t - off] : 0;
    __syncthreads();
    sc[t] += x;
    __syncthreads();
  }
  pex[t] = sc[t] - v;  // exclusive prefix within bucket
  int row = bin * 256 + t;
  if (row < N_NODES) {
    row_start[row] = base + pex[t];
    dis[row] = rsqrtf((float)(v + 1));
  }
  __syncthreads();
  for (int i = t; i < n; i += 256) {
    int e = ebuf[base + i];
    int rl = e >> 16;
    int rk = atomicAdd(&fl[rl], 1);
    col_sorted[base + pex[rl] + rk] = e & 0xFFFF;
  }
}

// ---------------- fused W transposes to bf16 ----------------
__global__ void k_wt_all(const float* __restrict__ W0, const float* __restrict__ W1,
                         const float* __restrict__ W2, ushort* __restrict__ Wt0,
                         ushort* __restrict__ Wt1, ushort* __restrict__ Wt2) {
  int idx = blockIdx.x * 256 + threadIdx.x;
  if (idx < 65536) {
    int n = idx >> 8, k = idx & 255;
    Wt0[idx] = f2bf(W0[k * 256 + n]);
  } else if (idx < 131072) {
    int l = idx - 65536;
    int n = l >> 8, k = l & 255;
    Wt1[l] = f2bf(W1[k * 256 + n]);
  } else if (idx < 163840) {
    int l = idx - 131072;
    int n = l >> 8, k = l & 255;  // n in [0,128)
    Wt2[l] = f2bf(W2[k * 128 + n]);
  }
}

// ---------------- bf16 MFMA GEMM, BK=64: hs = cvt( f(A) @ W * d_isqrt ) ----------------
template <int D, bool APPLY_BN, bool OUT_FP8>
__global__ __launch_bounds__(128 * (D / 64)) void k_gemm_bf16(const void* __restrict__ Av,
                                                              const ushort* __restrict__ Wt,
                                                              const float* __restrict__ ss,
                                                              const float* __restrict__ dis,
                                                              void* __restrict__ hsv) {
  constexpr int THREADS = 128 * (D / 64);  // 512 (D=256) / 256 (D=128)
  constexpr int BM = 128, BK = 64, K = 256;
  constexpr int WC = D / 64;
  constexpr int LDP = BK + 8;  // 72 bf16 (144B) stride
  __shared__ ushort As[BM * LDP];
  __shared__ ushort Bs[D * LDP];
  const int tid = threadIdx.x;
  const int lane = tid & 63;
  const int wid = tid >> 6;
  const int wr = wid / WC, wc = wid % WC;
  const int rb = blockIdx.x * BM;

  f32x4 acc[4][4];
#pragma unroll
  for (int m = 0; m < 4; ++m)
#pragma unroll
    for (int n = 0; n < 4; ++n) acc[m][n] = (f32x4)(0.f);

  for (int kt = 0; kt < K; kt += BK) {
    // stage A: 128 rows x 64 k = 1024 short8 tasks
#pragma unroll
    for (int it = 0; it < 1024 / THREADS; ++it) {
      int idx = tid + it * THREADS;
      int row = idx >> 3, kq = idx & 7;
      int gr = rb + row;
      if (gr >= N_NODES) gr = N_NODES - 1;
      float e[8];
      if constexpr (APPLY_BN) {
        const ushort* A = (const ushort*)Av;
        short8 v = *reinterpret_cast<const short8*>(&A[(size_t)gr * K + kt + kq * 8]);
#pragma unroll
        for (int q = 0; q < 8; ++q) {
          int k = kt + kq * 8 + q;
          e[q] = fmaxf(bf2f((ushort)v[q]) * ss[k] + ss[256 + k], 0.f);
        }
      } else {
        const float* A = (const float*)Av;
        const float4* src = reinterpret_cast<const float4*>(&A[(size_t)gr * K + kt + kq * 8]);
        float4 v0 = src[0], v1 = src[1];
        e[0] = v0.x; e[1] = v0.y; e[2] = v0.z; e[3] = v0.w;
        e[4] = v1.x; e[5] = v1.y; e[6] = v1.z; e[7] = v1.w;
      }
      short8 pk;
#pragma unroll
      for (int q = 0; q < 8; ++q) pk[q] = (short)f2bf(e[q]);
      *reinterpret_cast<short8*>(&As[row * LDP + kq * 8]) = pk;
    }
    // stage B: D rows x 64 k = D*8 short8 tasks
#pragma unroll
    for (int it = 0; it < D * 8 / THREADS; ++it) {
      int idx = tid + it * THREADS;
      int n = idx >> 3, kq = idx & 7;
      short8 v = *reinterpret_cast<const short8*>(&Wt[(size_t)n * K + kt + kq * 8]);
      *reinterpret_cast<short8*>(&Bs[n * LDP + kq * 8]) = v;
    }
    __syncthreads();

    const int rl = lane & 15;
#pragma unroll
    for (int ks = 0; ks < 2; ++ks) {
      const int kb = ks * 32 + (lane >> 4) * 8;
      short8 af[4], bfr[4];
#pragma unroll
      for (int f = 0; f < 4; ++f) {
        af[f] = *reinterpret_cast<short8*>(&As[(wr * 64 + f * 16 + rl) * LDP + kb]);
        bfr[f] = *reinterpret_cast<short8*>(&Bs[(wc * 64 + f * 16 + rl) * LDP + kb]);
      }
#pragma unroll
      for (int m = 0; m < 4; ++m)
#pragma unroll
        for (int n = 0; n < 4; ++n)
          acc[m][n] = __builtin_amdgcn_mfma_f32_16x16x32_bf16(af[m], bfr[n], acc[m][n], 0, 0, 0);
    }
    __syncthreads();
  }

  const int cl = lane & 15;
  const int rq = lane >> 4;
#pragma unroll
  for (int m = 0; m < 4; ++m) {
    int rbase = rb + wr * 64 + m * 16 + rq * 4;
#pragma unroll
    for (int j = 0; j < 4; ++j) {
      int row = rbase + j;
      if (row >= N_NODES) continue;
      float di = dis[row];
#pragma unroll
      for (int n = 0; n < 4; ++n) {
        int col = wc * 64 + n * 16 + cl;
        if constexpr (OUT_FP8) {
          ((uchar*)hsv)[(size_t)row * D + col] = f2fp8(acc[m][n][j] * di);
        } else {
          ((ushort*)hsv)[(size_t)row * D + col] = f2bf(acc[m][n][j] * di);
        }
      }
    }
  }
}

// ---------------- fp8 aggregation: pre = bf16(dis*(self+sum_nbr)+b) ----------------
__global__ __launch_bounds__(256) void k_agg_fp8(const uchar* __restrict__ hs8,
                                                 const int* __restrict__ cs,
                                                 const int* __restrict__ rs,
                                                 const float* __restrict__ dis,
                                                 const float* __restrict__ bias,
                                                 ushort* __restrict__ pre) {
  int gw = (blockIdx.x * 256 + threadIdx.x) >> 6;
  if (gw >= N_NODES) return;
  const int lane = threadIdx.x & 63;
  const int quad = lane >> 4;
  const int c16 = lane & 15;
  const size_t coff = (size_t)c16 * 16;

  float a[16];
  {
    uint4 sv = *reinterpret_cast<const uint4*>(&hs8[(size_t)gw * 256 + coff]);
    float tmp[16];
    dec4(sv.x, tmp);
    dec4(sv.y, tmp + 4);
    dec4(sv.z, tmp + 8);
    dec4(sv.w, tmp + 12);
#pragma unroll
    for (int q = 0; q < 16; ++q) a[q] = quad ? 0.f : tmp[q];
  }

  int s = rs[gw], e = rs[gw + 1];
  for (int base = s; base < e; base += 64) {
    int nav = min(64, e - base);
    int idx = (base + lane < e) ? cs[base + lane] : 0;
    int j = 0;
    for (; j + 16 <= nav; j += 16) {  // 16 edges: 4 loads in flight
      uint4 v[4];
#pragma unroll
      for (int u = 0; u < 4; ++u) {
        int c = __shfl(idx, j + 4 * u + quad);
        v[u] = *reinterpret_cast<const uint4*>(&hs8[(size_t)((uint)c) * 256 + coff]);
      }
#pragma unroll
      for (int u = 0; u < 4; ++u) {
        float tmp[16];
        dec4(v[u].x, tmp);
        dec4(v[u].y, tmp + 4);
        dec4(v[u].z, tmp + 8);
        dec4(v[u].w, tmp + 12);
#pragma unroll
        for (int q = 0; q < 16; ++q) a[q] += tmp[q];
      }
    }
    for (; j < nav; j += 4) {  // tail: weight-folded quad-load
      int je = j + quad;
      int c = __shfl(idx, je & 63);
      float w = (je < nav) ? 1.f : 0.f;
      uint4 v = *reinterpret_cast<const uint4*>(&hs8[(size_t)((uint)c) * 256 + coff]);
      float tmp[16];
      dec4(v.x, tmp);
      dec4(v.y, tmp + 4);
      dec4(v.z, tmp + 8);
      dec4(v.w, tmp + 12);
#pragma unroll
      for (int q = 0; q < 16; ++q) a[q] = fmaf(w, tmp[q], a[q]);
    }
  }
#pragma unroll
  for (int q = 0; q < 16; ++q) {
    a[q] += __shfl_xor(a[q], 16);
    a[q] += __shfl_xor(a[q], 32);
  }

  if (quad == 0) {
    float di = dis[gw];
    float bb[16];
#pragma unroll
    for (int p = 0; p < 4; ++p) {
      float4 b = *reinterpret_cast<const float4*>(&bias[coff + p * 4]);
      bb[p * 4] = b.x;
      bb[p * 4 + 1] = b.y;
      bb[p * 4 + 2] = b.z;
      bb[p * 4 + 3] = b.w;
    }
    short8 o0, o1;
#pragma unroll
    for (int q = 0; q < 8; ++q) {
      o0[q] = (short)f2bf(a[q] * di + bb[q]);
      o1[q] = (short)f2bf(a[8 + q] * di + bb[8 + q]);
    }
    *reinterpret_cast<short8*>(&pre[(size_t)gw * 256 + coff]) = o0;
    *reinterpret_cast<short8*>(&pre[(size_t)gw * 256 + coff + 8]) = o1;
  }
}

// layer-3 agg + log_softmax: D=128 bf16 row = 256B = 16 lanes x short8; 4 edges/instr.
__global__ __launch_bounds__(256) void k_agg_lsm_bf16(const ushort* __restrict__ hs,
                                                      const int* __restrict__ cs,
                                                      const int* __restrict__ rs,
                                                      const float* __restrict__ dis,
                                                      const float* __restrict__ bias,
                                                      float* __restrict__ out) {
  int gw = (blockIdx.x * 256 + threadIdx.x) >> 6;
  if (gw >= N_NODES) return;
  const int lane = threadIdx.x & 63;
  const int quad = lane >> 4;
  const int c8 = lane & 15;
  const size_t coff = (size_t)c8 * 8;

  float a[8];
  short8 sv = *reinterpret_cast<const short8*>(&hs[(size_t)gw * 128 + coff]);
#pragma unroll
  for (int q = 0; q < 8; ++q) a[q] = quad ? 0.f : bf2f((ushort)sv[q]);

  int s = rs[gw], e = rs[gw + 1];
  for (int base = s; base < e; base += 64) {
    int nav = min(64, e - base);
    int idx = (base + lane < e) ? cs[base + lane] : 0;
    int j = 0;
    for (; j + 16 <= nav; j += 16) {
      short8 v[4];
#pragma unroll
      for (int u = 0; u < 4; ++u) {
        int c = __shfl(idx, j + 4 * u + quad);
        v[u] = *reinterpret_cast<const short8*>(&hs[(size_t)((uint)c) * 128 + coff]);
      }
#pragma unroll
      for (int u = 0; u < 4; ++u)
#pragma unroll
        for (int q = 0; q < 8; ++q) a[q] += bf2f((ushort)v[u][q]);
    }
    for (; j < nav; j += 4) {
      int je = j + quad;
      int c = __shfl(idx, je & 63);
      float w = (je < nav) ? 1.f : 0.f;
      short8 v = *reinterpret_cast<const short8*>(&hs[(size_t)((uint)c) * 128 + coff]);
#pragma unroll
      for (int q = 0; q < 8; ++q) a[q] = fmaf(w, bf2f((ushort)v[q]), a[q]);
    }
  }
#pragma unroll
  for (int q = 0; q < 8; ++q) {
    a[q] += __shfl_xor(a[q], 16);
    a[q] += __shfl_xor(a[q], 32);
  }

  float di = dis[gw];
  float4 b0 = *reinterpret_cast<const float4*>(&bias[c8 * 8]);
  float4 b1 = *reinterpret_cast<const float4*>(&bias[c8 * 8 + 4]);
  float bb[8] = {b0.x, b0.y, b0.z, b0.w, b1.x, b1.y, b1.z, b1.w};
  float vv[8];
  float m = -1e30f;
#pragma unroll
  for (int q = 0; q < 8; ++q) {
    vv[q] = a[q] * di + bb[q];
    m = fmaxf(m, vv[q]);
  }
#pragma unroll
  for (int o = 1; o < 16; o <<= 1) m = fmaxf(m, __shfl_xor(m, o));
  float sum = 0.f;
#pragma unroll
  for (int q = 0; q < 8; ++q) sum += __expf(vv[q] - m);
#pragma unroll
  for (int o = 1; o < 16; o <<= 1) sum += __shfl_xor(sum, o);
  float ls = m + logf(sum);
  if (quad == 0) {
    float4 o0 = {vv[0] - ls, vv[1] - ls, vv[2] - ls, vv[3] - ls};
    float4 o1 = {vv[4] - ls, vv[5] - ls, vv[6] - ls, vv[7] - ls};
    *reinterpret_cast<float4*>(&out[(size_t)gw * 128 + coff]) = o0;
    *reinterpret_cast<float4*>(&out[(size_t)gw * 128 + coff + 4]) = o1;
  }
}

// ---------------- batchnorm stats: three-phase, atomic-free ----------------
__global__ __launch_bounds__(256) void k_bnstatsA(const ushort* __restrict__ pre,
                                                  float* __restrict__ partial) {
  int t = threadIdx.x;
  int rsub = t >> 7;
  int cp = (t & 127) * 2;
  float s0 = 0.f, s1 = 0.f, q0 = 0.f, q1 = 0.f;
  for (int r = blockIdx.x * 2 + rsub; r < N_NODES; r += BNA_BLOCKS * 2) {
    ushort2 v = *reinterpret_cast<const ushort2*>(&pre[(size_t)r * 256 + cp]);
    float f0 = bf2f(v.x), f1 = bf2f(v.y);
    s0 += f0;
    q0 += f0 * f0;
    s1 += f1;
    q1 += f1 * f1;
  }
  __shared__ float lsum[256], lsq[256];
  if (rsub) {
    lsum[cp] = s0;
    lsum[cp + 1] = s1;
    lsq[cp] = q0;
    lsq[cp + 1] = q1;
  }
  __syncthreads();
  if (!rsub) {
    float* p = &partial[(size_t)blockIdx.x * 512];
    p[cp] = s0 + lsum[cp];
    p[cp + 1] = s1 + lsum[cp + 1];
    p[256 + cp] = q0 + lsq[cp];
    p[256 + cp + 1] = q1 + lsq[cp + 1];
  }
}

__global__ __launch_bounds__(512) void k_bnstatsB(const float* __restrict__ partial,
                                                  float* __restrict__ p2) {
  int t = threadIdx.x, b = blockIdx.x;
  float a = 0.f;
#pragma unroll 8
  for (int r = 0; r < BNA_BLOCKS / 8; ++r)
    a += partial[(size_t)(b * (BNA_BLOCKS / 8) + r) * 512 + t];
  p2[(size_t)b * 512 + t] = a;
}

__global__ void k_bnfinal(const float* __restrict__ p2, const float* __restrict__ gamma,
                          const float* __restrict__ beta, float* __restrict__ ss) {
  int t = threadIdx.x;
  float sum = 0.f, sq = 0.f;
#pragma unroll
  for (int b = 0; b < 8; ++b) {
    sum += p2[(size_t)b * 512 + t];
    sq += p2[(size_t)b * 512 + 256 + t];
  }
  float mu = sum * (1.f / N_NODES);
  float var = sq * (1.f / N_NODES) - mu * mu;
  float sc = gamma[t] * rsqrtf(var + BN_EPS);
  ss[t] = sc;
  ss[256 + t] = beta[t] - mu * sc;
}

// ---------------- launcher ----------------
extern "C" void kernel_launch(void* const* d_in, const int* in_sizes, int n_in,
                              void* d_out, int out_size, void* d_ws, size_t ws_size,
                              hipStream_t stream) {
  const float* x = (const float*)d_in[0];
  const int* erow = (const int*)d_in[1];
  const int* ecol = erow + N_EDGES;
  const float* W0 = (const float*)d_in[2];
  const float* b0 = (const float*)d_in[3];
  const float* W1 = (const float*)d_in[4];
  const float* b1 = (const float*)d_in[5];
  const float* W2 = (const float*)d_in[6];
  const float* b2 = (const float*)d_in[7];
  const float* g0 = (const float*)d_in[8];
  const float* be0 = (const float*)d_in[9];
  const float* g1 = (const float*)d_in[10];
  const float* be1 = (const float*)d_in[11];
  float* out = (float*)d_out;

  char* ws = (char*)d_ws;
  size_t off = 0;
  auto take = [&](size_t bytes) {
    char* p = ws + off;
    off = (off + bytes + 255) & ~(size_t)255;
    return p;
  };
  int* bh = (int*)take(256 * 256 * 4);
  int* bhoff = (int*)take(256 * 256 * 4);
  int* btot = (int*)take(256 * 4);
  int* bucketStart = (int*)take(256 * 4);
  int* ebuf = (int*)take((size_t)N_EDGES * 4);
  int* row_start = (int*)take((N_NODES + 1) * 4);
  float* bnpart = (float*)take((size_t)BNA_BLOCKS * 512 * 4);
  float* bnpart2 = (float*)take(8 * 512 * 4);
  float* dis = (float*)take(N_NODES * 4);
  float* ss0 = (float*)take(512 * 4);
  float* ss1 = (float*)take(512 * 4);
  ushort* Wt0 = (ushort*)take(256 * 256 * 2);
  ushort* Wt1 = (ushort*)take(256 * 256 * 2);
  ushort* Wt2 = (ushort*)take(256 * 128 * 2);
  int* col_sorted = (int*)take((size_t)N_EDGES * 4);
  uchar* hs8 = (uchar*)take((size_t)N_NODES * 256);        // fp8 gather operand (L0/L1)
  ushort* hs = (ushort*)take((size_t)N_NODES * 128 * 2);   // bf16 (L2)
  ushort* pre = (ushort*)take((size_t)N_NODES * 256 * 2);  // bf16
  if (off > ws_size) return;

  // CSR build: radix sort by row, no global atomics, no memset
  k_ehist<<<EBLK, 256, 0, stream>>>(erow, bh);
  k_binscanA<<<256, 256, 0, stream>>>(bh, bhoff, btot, EBLK);
  k_binscanB<<<1, 256, 0, stream>>>(btot, bucketStart, row_start);
  k_escatter<<<EBLK, 256, 0, stream>>>(erow, ecol, bucketStart, bhoff, ebuf);
  k_esort<<<NBUCK, 256, 0, stream>>>(ebuf, bucketStart, btot, col_sorted, row_start, dis);

  k_wt_all<<<640, 256, 0, stream>>>(W0, W1, W2, Wt0, Wt1, Wt2);

  int mblocks = (N_NODES + 127) / 128;        // 391
  int agg_grid = (N_NODES * 64 + 255) / 256;  // 12500
  // layer 0 (hs fp8)
  k_gemm_bf16<256, false, true><<<mblocks, 512, 0, stream>>>(x, Wt0, nullptr, dis, hs8);
  k_agg_fp8<<<agg_grid, 256, 0, stream>>>(hs8, col_sorted, row_start, dis, b0, pre);
  k_bnstatsA<<<BNA_BLOCKS, 256, 0, stream>>>(pre, bnpart);
  k_bnstatsB<<<8, 512, 0, stream>>>(bnpart, bnpart2);
  k_bnfinal<<<1, 256, 0, stream>>>(bnpart2, g0, be0, ss0);
  // layer 1 (hs fp8)
  k_gemm_bf16<256, true, true><<<mblocks, 512, 0, stream>>>(pre, Wt1, ss0, dis, hs8);
  k_agg_fp8<<<agg_grid, 256, 0, stream>>>(hs8, col_sorted, row_start, dis, b1, pre);
  k_bnstatsA<<<BNA_BLOCKS, 256, 0, stream>>>(pre, bnpart);
  k_bnstatsB<<<8, 512, 0, stream>>>(bnpart, bnpart2);
  k_bnfinal<<<1, 256, 0, stream>>>(bnpart2, g1, be1, ss1);
  // layer 2 (bf16) + fused log_softmax
  k_gemm_bf16<128, true, false><<<mblocks, 256, 0, stream>>>(pre, Wt2, ss1, dis, hs);
  k_agg_lsm_bf16<<<agg_grid, 256, 0, stream>>>(hs, col_sorted, row_start, dis, b2, out);
}